// Round 5
// baseline (426.740 us; speedup 1.0000x reference)
//
#include <hip/hip_runtime.h>

#define N_TOK   32768
#define NEMBED  1024
#define SCALE   32.0f   // sqrt(1024)
#define TM      16      // tokens per tile

// static grid partition (4 blocks/CU target, 1024 blocks total)
#define G0 64
#define G1 288
#define G2 576
#define G3 96
#define GRID (G0 + G1 + G2 + G3)   // 1024

__device__ __forceinline__ int bucket_of(int idx) {
    return (idx < 20000) ? 0 : (idx < 40000) ? 1 : (idx < 200000) ? 2 : 3;
}

__device__ __forceinline__ int swz(int f4) { return f4 ^ ((f4 >> 3) & 7); }

// ---------------- classify + compact tokens into per-bucket lists ----------------
__global__ void classify_kernel(const int* __restrict__ x,
                                int* __restrict__ cnt,      // [4]
                                int* __restrict__ lists) {  // [4][N_TOK]
    __shared__ int s_cnt[4], s_base[4];
    int tid = threadIdx.x;
    if (tid < 4) s_cnt[tid] = 0;
    __syncthreads();
    int t = blockIdx.x * blockDim.x + tid;
    int b = 0, p = 0;
    if (t < N_TOK) {
        b = bucket_of(x[t]);
        p = atomicAdd(&s_cnt[b], 1);
    }
    __syncthreads();
    if (tid < 4) s_base[tid] = atomicAdd(&cnt[tid], s_cnt[tid]);
    __syncthreads();
    if (t < N_TOK) lists[b * N_TOK + s_base[b] + p] = t;
}

// ---------------- bucket 0: row copy ----------------
__device__ __forceinline__ void run_copy(const int* __restrict__ x,
                                         const float* __restrict__ table0,
                                         const int* __restrict__ list0,
                                         float* __restrict__ out,
                                         int n, int tile0, int stride,
                                         int* s_tok, int* s_row) {
    int ntiles = (n + TM - 1) / TM;
    int tid = threadIdx.x;
    #pragma unroll 1
    for (int t = tile0; t < ntiles; t += stride) {
        if (tid < TM) {
            int i = t * TM + tid;
            int tok = (i < n) ? list0[i] : -1;
            s_tok[tid] = tok;
            s_row[tid] = (tok >= 0) ? x[tok] : -1;
        }
        __syncthreads();
        const float4* t4 = (const float4*)table0;
        #pragma unroll 1
        for (int tt = 0; tt < TM; tt++) {
            int tok = s_tok[tt];
            if (tok >= 0) {
                float4 v = t4[(size_t)s_row[tt] * 256 + tid];
                v.x *= SCALE; v.y *= SCALE; v.z *= SCALE; v.w *= SCALE;
                ((float4*)out)[(size_t)tok * 256 + tid] = v;
            }
        }
        __syncthreads();
    }
}

// ---------------- buckets 1..3: pipelined gather-GEMM ----------------
// TW==16: wave tg owns cols [256*tg, 256*tg+256), all 16 tokens. (no redundancy)
// TW==4 : tile = (chunk, cs); all waves share cols [256*cs, ...); wave tg owns tokens [4tg,4tg+4).
template <int D, int TW>
__device__ __forceinline__ void run_proj(const int* __restrict__ x,
                                         const float* __restrict__ table,
                                         const float* __restrict__ proj,
                                         const int* __restrict__ list_b,
                                         float* __restrict__ out,
                                         int n, int start, int ntiles,
                                         int tile0, int stride,
                                         float* __restrict__ E,   // [2][TM*D]
                                         int* __restrict__ s_tok, // [2][TM]
                                         int* __restrict__ s_row) // [2][TM]
{
    constexpr int D4   = D / 4;
    constexpr int NF4  = TM * D / 4;                 // total float4 per E tile
    constexpr int F4PT = (NF4 >= 256) ? NF4 / 256 : 1;
    constexpr int ATH  = NF4 / F4PT;                 // active staging threads

    int tid = threadIdx.x;
    int myN = (tile0 < ntiles) ? ((ntiles - 1 - tile0) / stride + 1) : 0;
    if (myN == 0) return;

    float4 ereg[F4PT];

    // ---- prologue: ids(0), ids(1); stage E(0) -> buf0
    if (tid < TM) {
        int t0 = tile0;
        int ch = (TW == 4) ? (t0 >> 2) : t0;
        int i  = ch * TM + tid;
        int tok = (i < n) ? list_b[i] : -1;
        s_tok[tid] = tok;
        s_row[tid] = (tok >= 0) ? (x[tok] - start) : -1;
        if (myN > 1) {
            int t1 = tile0 + stride;
            int ch1 = (TW == 4) ? (t1 >> 2) : t1;
            int i1  = ch1 * TM + tid;
            int tok1 = (i1 < n) ? list_b[i1] : -1;
            s_tok[TM + tid] = tok1;
            s_row[TM + tid] = (tok1 >= 0) ? (x[tok1] - start) : -1;
        }
    }
    __syncthreads();
    if (tid < ATH) {
        float4* B = (float4*)E;
        #pragma unroll
        for (int q = 0; q < F4PT; q++) {
            int f4 = tid * F4PT + q;
            int row = s_row[f4 / D4];
            ereg[q] = (row >= 0) ? *(const float4*)&table[(size_t)row * D + (f4 % D4) * 4]
                                 : make_float4(0.f, 0.f, 0.f, 0.f);
            B[swz(f4)] = ereg[q];
        }
    }
    __syncthreads();

    #pragma unroll 1
    for (int ti = 0; ti < myN; ++ti) {
        int c = ti & 1;
        int tile = tile0 + ti * stride;
        int cs = (TW == 4) ? (tile & 3) : 0;
        bool hn = (ti + 1 < myN);
        bool h2 = (ti + 2 < myN);

        // issue E(ti+1) gather -> regs (rows from the other id slot)
        if (hn && tid < ATH) {
            #pragma unroll
            for (int q = 0; q < F4PT; q++) {
                int f4 = tid * F4PT + q;
                int row = s_row[(c ^ 1) * TM + f4 / D4];
                ereg[q] = (row >= 0) ? *(const float4*)&table[(size_t)row * D + (f4 % D4) * 4]
                                     : make_float4(0.f, 0.f, 0.f, 0.f);
            }
        }
        // issue list load for ids(ti+2)
        int lreg = -1;
        if (h2 && tid < TM) {
            int t2 = tile0 + (ti + 2) * stride;
            int ch2 = (TW == 4) ? (t2 >> 2) : t2;
            int i2  = ch2 * TM + tid;
            lreg = (i2 < n) ? list_b[i2] : -1;
        }

        // ---- compute tile ti from buf c
        {
            const float4* Ec = (const float4*)(E + c * (TM * D));
            int lane = tid & 63, tg = tid >> 6;
            int col = (TW == 16) ? (tg * 256 + lane * 4) : (cs * 256 + lane * 4);
            int rowbase = (TW == 16) ? 0 : tg * 4;
            float4 acc[TW];
            #pragma unroll
            for (int j = 0; j < TW; j++) acc[j] = make_float4(0.f, 0.f, 0.f, 0.f);

            #pragma unroll 2
            for (int kg = 0; kg < D4; ++kg) {
                float4 p0 = *(const float4*)&proj[(size_t)(4 * kg + 0) * NEMBED + col];
                float4 p1 = *(const float4*)&proj[(size_t)(4 * kg + 1) * NEMBED + col];
                float4 p2 = *(const float4*)&proj[(size_t)(4 * kg + 2) * NEMBED + col];
                float4 p3 = *(const float4*)&proj[(size_t)(4 * kg + 3) * NEMBED + col];
                #pragma unroll
                for (int j = 0; j < TW; j++) {
                    float4 e = Ec[swz((rowbase + j) * D4 + kg)];   // wave-uniform broadcast
                    acc[j].x += e.x * p0.x + e.y * p1.x + e.z * p2.x + e.w * p3.x;
                    acc[j].y += e.x * p0.y + e.y * p1.y + e.z * p2.y + e.w * p3.y;
                    acc[j].z += e.x * p0.z + e.y * p1.z + e.z * p2.z + e.w * p3.z;
                    acc[j].w += e.x * p0.w + e.y * p1.w + e.z * p2.w + e.w * p3.w;
                }
            }
            #pragma unroll
            for (int j = 0; j < TW; j++) {
                int tok = s_tok[c * TM + rowbase + j];
                if (tok >= 0) {
                    float4 v = acc[j];
                    v.x *= SCALE; v.y *= SCALE; v.z *= SCALE; v.w *= SCALE;
                    *(float4*)&out[(size_t)tok * NEMBED + col] = v;
                }
            }
        }

        // resolve ids(ti+2): x gather (overlaps with barrier + ds_write below)
        int tok2 = -1, row2 = -1;
        if (h2 && tid < TM) {
            tok2 = lreg;
            row2 = (lreg >= 0) ? (x[lreg] - start) : -1;
        }
        __syncthreads();
        if (hn && tid < ATH) {
            float4* B = (float4*)(E + (c ^ 1) * (TM * D));
            #pragma unroll
            for (int q = 0; q < F4PT; q++) B[swz(tid * F4PT + q)] = ereg[q];
        }
        if (h2 && tid < TM) {
            s_tok[c * TM + tid] = tok2;
            s_row[c * TM + tid] = row2;
        }
        __syncthreads();
    }
}

// ---------------- fused kernel: static block partition, uniform per-block type ----------------
__global__ __launch_bounds__(256, 4)
void fused_embed_kernel(const int* __restrict__ x,
                        const float* __restrict__ t0, const float* __restrict__ t1,
                        const float* __restrict__ t2, const float* __restrict__ t3,
                        const float* __restrict__ p1, const float* __restrict__ p2,
                        const float* __restrict__ p3,
                        const int* __restrict__ cnt,
                        const int* __restrict__ lists,
                        float* __restrict__ out) {
    __shared__ float E[2 * TM * 256];      // 32 KB double buffer (max D=256)
    __shared__ int s_tok[2 * TM], s_row[2 * TM];

    int bid = blockIdx.x;
    if (bid < G0) {
        run_copy(x, t0, lists, out, cnt[0], bid, G0, s_tok, s_row);
    } else if (bid < G0 + G1) {
        int n = cnt[1];
        int ntiles = ((n + TM - 1) / TM) * 4;   // x4 col-slices
        run_proj<256, 4>(x, t1, p1, lists + 1 * N_TOK, out, n, 20000,
                         ntiles, bid - G0, G1, E, s_tok, s_row);
    } else if (bid < G0 + G1 + G2) {
        int n = cnt[2];
        int ntiles = (n + TM - 1) / TM;
        run_proj<64, 16>(x, t2, p2, lists + 2 * N_TOK, out, n, 40000,
                         ntiles, bid - (G0 + G1), G2, E, s_tok, s_row);
    } else {
        int n = cnt[3];
        int ntiles = (n + TM - 1) / TM;
        run_proj<16, 16>(x, t3, p3, lists + 3 * N_TOK, out, n, 200000,
                         ntiles, bid - (G0 + G1 + G2), G3, E, s_tok, s_row);
    }
}

extern "C" void kernel_launch(void* const* d_in, const int* in_sizes, int n_in,
                              void* d_out, int out_size, void* d_ws, size_t ws_size,
                              hipStream_t stream) {
    const int*   x  = (const int*)d_in[0];
    const float* t0 = (const float*)d_in[1];
    const float* t1 = (const float*)d_in[2];
    const float* t2 = (const float*)d_in[3];
    const float* t3 = (const float*)d_in[4];
    const float* p1 = (const float*)d_in[5];
    const float* p2 = (const float*)d_in[6];
    const float* p3 = (const float*)d_in[7];
    float* out = (float*)d_out;

    int* cnt   = (int*)d_ws;          // [4] (+ padding to 64 ints)
    int* lists = cnt + 64;            // [4][N_TOK]

    hipMemsetAsync(d_ws, 0, 64 * sizeof(int), stream);
    classify_kernel<<<N_TOK / 256, 256, 0, stream>>>(x, cnt, lists);

    fused_embed_kernel<<<GRID, 256, 0, stream>>>(x, t0, t1, t2, t3, p1, p2, p3,
                                                 cnt, lists, out);
}

// Round 6
// 95.853 us; speedup vs baseline: 4.4520x; 4.4520x over previous
//
#include <hip/hip_runtime.h>

#define N_TOK    32768
#define NEMBED   1024
#define SCALE    32.0f   // sqrt(1024)
#define NTHREADS 512     // 8 waves per block

// static grid partition (2 blocks/CU resident; 1024 = 2 generations)
#define G0 64
#define G1 320
#define G2 512    // multiple of 4 (cs slices)
#define G3 128    // multiple of 4
#define GRID (G0 + G1 + G2 + G3)   // 1024

__device__ __forceinline__ int bucket_of(int idx) {
    return (idx < 20000) ? 0 : (idx < 40000) ? 1 : (idx < 200000) ? 2 : 3;
}

// ---------------- classify + compact tokens into per-bucket lists ----------------
__global__ void classify_kernel(const int* __restrict__ x,
                                int* __restrict__ cnt,      // [4]
                                int* __restrict__ lists) {  // [4][N_TOK]
    __shared__ int s_cnt[4], s_base[4];
    int tid = threadIdx.x;
    if (tid < 4) s_cnt[tid] = 0;
    __syncthreads();
    int t = blockIdx.x * blockDim.x + tid;
    int b = 0, p = 0;
    if (t < N_TOK) {
        b = bucket_of(x[t]);
        p = atomicAdd(&s_cnt[b], 1);
    }
    __syncthreads();
    if (tid < 4) s_base[tid] = atomicAdd(&cnt[tid], s_cnt[tid]);
    __syncthreads();
    if (t < N_TOK) lists[b * N_TOK + s_base[b] + p] = t;
}

// ---------------- bucket 0: row copy, chunks of 32 tokens ----------------
__device__ __forceinline__ void run_copy(const int* __restrict__ x,
                                         const float* __restrict__ table0,
                                         const int* __restrict__ list0,
                                         float* __restrict__ out,
                                         int n, int tile0, int stride,
                                         int* s_tok, int* s_row) {
    int ntiles = (n + 31) / 32;
    int tid = threadIdx.x;
    const float4* t4 = (const float4*)table0;
    float4* o4 = (float4*)out;
    #pragma unroll 1
    for (int t = tile0; t < ntiles; t += stride) {
        if (tid < 32) {
            int i = t * 32 + tid;
            int tok = (i < n) ? list0[i] : -1;
            s_tok[tid] = tok;
            s_row[tid] = (tok >= 0) ? x[tok] : -1;
        }
        __syncthreads();
        #pragma unroll 1
        for (int q = 0; q < 16; ++q) {
            int f4 = q * NTHREADS + tid;          // 0..8191 = 32 tok x 256 f4
            int tt = f4 >> 8, c4 = f4 & 255;
            int tok = s_tok[tt];
            if (tok >= 0) {
                float4 v = t4[(size_t)s_row[tt] * 256 + c4];
                v.x *= SCALE; v.y *= SCALE; v.z *= SCALE; v.w *= SCALE;
                o4[(size_t)tok * 256 + c4] = v;
            }
        }
        __syncthreads();
    }
}

// ---------------- buckets 2/3: proj slice in LDS, fixed cs per block ----------------
// chunk = 32 tokens; 8 waves x 4 tokens; lane owns float4 of cols [cs*256 .. +256)
template <int D>
__device__ __forceinline__ void run_proj_lds(const int* __restrict__ x,
                                             const float* __restrict__ table,
                                             const float* __restrict__ proj,
                                             const int* __restrict__ list_b,
                                             float* __restrict__ out,
                                             int n, int start,
                                             int cs, int chunk0, int cstride,
                                             float* __restrict__ Pb,
                                             float* __restrict__ Eb,
                                             int* __restrict__ s_tok,
                                             int* __restrict__ s_row) {
    constexpr int D4   = D / 4;
    constexpr int NF4P = D * 64;          // proj-slice float4s (D rows x 256 cols)
    constexpr int QP   = NF4P / NTHREADS; // 8 for D=64, 2 for D=16
    constexpr int NF4E = 32 * D4;         // E-tile float4s (512 for D=64, 128 for D=16)

    int tid = threadIdx.x;
    int nchunk = (n + 31) / 32;
    int myN = (chunk0 < nchunk) ? ((nchunk - 1 - chunk0) / cstride + 1) : 0;
    if (myN == 0) return;

    float4* P4 = (float4*)Pb;
    float4* E4 = (float4*)Eb;
    const float4* pj4 = (const float4*)proj;
    const float4* tb4 = (const float4*)table;

    // one-time: stage proj slice [D][256] into LDS (coalesced)
    #pragma unroll
    for (int q = 0; q < QP; ++q) {
        int f4 = q * NTHREADS + tid;
        int r = f4 >> 6, c4 = f4 & 63;
        P4[f4] = pj4[(size_t)r * 256 + cs * 64 + c4];
    }
    // ids(0), ids(1)
    if (tid < 32) {
        int i = chunk0 * 32 + tid;
        int tok = (i < n) ? list_b[i] : -1;
        s_tok[tid] = tok;
        s_row[tid] = (tok >= 0) ? (x[tok] - start) : -1;
        if (myN > 1) {
            int i1 = (chunk0 + cstride) * 32 + tid;
            int tok1 = (i1 < n) ? list_b[i1] : -1;
            s_tok[32 + tid] = tok1;
            s_row[32 + tid] = (tok1 >= 0) ? (x[tok1] - start) : -1;
        }
    }
    __syncthreads();
    // E(0)
    if (tid < NF4E) {
        int row = s_row[tid / D4];
        E4[tid] = (row >= 0) ? tb4[(size_t)row * D4 + (tid % D4)]
                             : make_float4(0.f, 0.f, 0.f, 0.f);
    }
    __syncthreads();

    int w = tid >> 6, lane = tid & 63;
    int col = cs * 256 + lane * 4;

    #pragma unroll 1
    for (int ti = 0; ti < myN; ++ti) {
        int sl = ti & 1;
        bool hn = (ti + 1 < myN), h2 = (ti + 2 < myN);

        // issue E(ti+1) gather -> reg (uses ids slot sl^1); overlaps compute
        float4 ereg = make_float4(0.f, 0.f, 0.f, 0.f);
        if (hn && tid < NF4E) {
            int row = s_row[(sl ^ 1) * 32 + tid / D4];
            if (row >= 0) ereg = tb4[(size_t)row * D4 + (tid % D4)];
        }
        // issue list(ti+2)
        int lreg = -1;
        if (h2 && tid < 32) {
            int i2 = (chunk0 + (ti + 2) * cstride) * 32 + tid;
            lreg = (i2 < n) ? list_b[i2] : -1;
        }

        // compute chunk ti: pure LDS + FMA
        float4 acc[4];
        #pragma unroll
        for (int j = 0; j < 4; j++) acc[j] = make_float4(0.f, 0.f, 0.f, 0.f);
        #pragma unroll 2
        for (int kg = 0; kg < D4; ++kg) {
            float4 p0 = P4[(4 * kg + 0) * 64 + lane];
            float4 p1 = P4[(4 * kg + 1) * 64 + lane];
            float4 p2 = P4[(4 * kg + 2) * 64 + lane];
            float4 p3 = P4[(4 * kg + 3) * 64 + lane];
            #pragma unroll
            for (int j = 0; j < 4; j++) {
                float4 e = E4[(4 * w + j) * D4 + kg];   // wave-uniform broadcast
                acc[j].x += e.x * p0.x + e.y * p1.x + e.z * p2.x + e.w * p3.x;
                acc[j].y += e.x * p0.y + e.y * p1.y + e.z * p2.y + e.w * p3.y;
                acc[j].z += e.x * p0.z + e.y * p1.z + e.z * p2.z + e.w * p3.z;
                acc[j].w += e.x * p0.w + e.y * p1.w + e.z * p2.w + e.w * p3.w;
            }
        }
        #pragma unroll
        for (int j = 0; j < 4; j++) {
            int tok = s_tok[sl * 32 + 4 * w + j];
            if (tok >= 0) {
                float4 v = acc[j];
                v.x *= SCALE; v.y *= SCALE; v.z *= SCALE; v.w *= SCALE;
                *(float4*)&out[(size_t)tok * NEMBED + col] = v;
            }
        }
        // resolve ids(ti+2)
        int row2 = -1;
        if (h2 && tid < 32 && lreg >= 0) row2 = x[lreg] - start;
        __syncthreads();
        if (hn && tid < NF4E) E4[tid] = ereg;
        if (h2 && tid < 32) { s_tok[sl * 32 + tid] = lreg; s_row[sl * 32 + tid] = row2; }
        __syncthreads();
    }
}

// ---------------- bucket 1: D=256, proj from global (L2), col-split x4 by tile ----------------
// chunk = 16 tokens; tile = (chunk, cs); 8 waves x 2 tokens; lane owns float4 of cols
__device__ __forceinline__ void run_proj_g(const int* __restrict__ x,
                                           const float* __restrict__ table,
                                           const float* __restrict__ proj,
                                           const int* __restrict__ list_b,
                                           float* __restrict__ out,
                                           int n, int start,
                                           int tile0, int stride,
                                           float* __restrict__ Eb,
                                           int* __restrict__ s_tok,
                                           int* __restrict__ s_row) {
    constexpr int D4 = 64;
    int tid = threadIdx.x;
    int nchunk = (n + 15) / 16;
    int ntiles = nchunk * 4;
    int myN = (tile0 < ntiles) ? ((ntiles - 1 - tile0) / stride + 1) : 0;
    if (myN == 0) return;

    float4* E4 = (float4*)Eb;
    const float4* tb4 = (const float4*)table;

    if (tid < 16) {
        int i = (tile0 >> 2) * 16 + tid;
        int tok = (i < n) ? list_b[i] : -1;
        s_tok[tid] = tok;
        s_row[tid] = (tok >= 0) ? (x[tok] - start) : -1;
        if (myN > 1) {
            int i1 = ((tile0 + stride) >> 2) * 16 + tid;
            int tok1 = (i1 < n) ? list_b[i1] : -1;
            s_tok[32 + tid] = tok1;
            s_row[32 + tid] = (tok1 >= 0) ? (x[tok1] - start) : -1;
        }
    }
    __syncthreads();
    #pragma unroll
    for (int q = 0; q < 2; ++q) {                 // 1024 f4 = 16 tok x 64
        int f4 = tid * 2 + q;
        int row = s_row[f4 >> 6];
        E4[f4] = (row >= 0) ? tb4[(size_t)row * D4 + (f4 & 63)]
                            : make_float4(0.f, 0.f, 0.f, 0.f);
    }
    __syncthreads();

    int w = tid >> 6, lane = tid & 63;

    #pragma unroll 1
    for (int ti = 0; ti < myN; ++ti) {
        int sl = ti & 1;
        int tile = tile0 + ti * stride;
        int cs = tile & 3;
        bool hn = (ti + 1 < myN), h2 = (ti + 2 < myN);

        float4 er0 = make_float4(0.f, 0.f, 0.f, 0.f), er1 = er0;
        if (hn) {
            int f4a = tid * 2, f4b = tid * 2 + 1;
            int ra = s_row[(sl ^ 1) * 32 + (f4a >> 6)];
            int rb = s_row[(sl ^ 1) * 32 + (f4b >> 6)];
            if (ra >= 0) er0 = tb4[(size_t)ra * D4 + (f4a & 63)];
            if (rb >= 0) er1 = tb4[(size_t)rb * D4 + (f4b & 63)];
        }
        int lreg = -1;
        if (h2 && tid < 16) {
            int i2 = ((tile0 + (ti + 2) * stride) >> 2) * 16 + tid;
            lreg = (i2 < n) ? list_b[i2] : -1;
        }

        int col = cs * 256 + lane * 4;
        float4 acc0 = make_float4(0.f, 0.f, 0.f, 0.f), acc1 = acc0;
        #pragma unroll 2
        for (int kg = 0; kg < D4; ++kg) {
            float4 p0 = *(const float4*)&proj[(size_t)(4 * kg + 0) * NEMBED + col];
            float4 p1 = *(const float4*)&proj[(size_t)(4 * kg + 1) * NEMBED + col];
            float4 p2 = *(const float4*)&proj[(size_t)(4 * kg + 2) * NEMBED + col];
            float4 p3 = *(const float4*)&proj[(size_t)(4 * kg + 3) * NEMBED + col];
            float4 e0 = E4[(2 * w + 0) * D4 + kg];
            float4 e1 = E4[(2 * w + 1) * D4 + kg];
            acc0.x += e0.x * p0.x + e0.y * p1.x + e0.z * p2.x + e0.w * p3.x;
            acc0.y += e0.x * p0.y + e0.y * p1.y + e0.z * p2.y + e0.w * p3.y;
            acc0.z += e0.x * p0.z + e0.y * p1.z + e0.z * p2.z + e0.w * p3.z;
            acc0.w += e0.x * p0.w + e0.y * p1.w + e0.z * p2.w + e0.w * p3.w;
            acc1.x += e1.x * p0.x + e1.y * p1.x + e1.z * p2.x + e1.w * p3.x;
            acc1.y += e1.x * p0.y + e1.y * p1.y + e1.z * p2.y + e1.w * p3.y;
            acc1.z += e1.x * p0.z + e1.y * p1.z + e1.z * p2.z + e1.w * p3.z;
            acc1.w += e1.x * p0.w + e1.y * p1.w + e1.z * p2.w + e1.w * p3.w;
        }
        int tokA = s_tok[sl * 32 + 2 * w], tokB = s_tok[sl * 32 + 2 * w + 1];
        if (tokA >= 0) {
            float4 v = acc0;
            v.x *= SCALE; v.y *= SCALE; v.z *= SCALE; v.w *= SCALE;
            *(float4*)&out[(size_t)tokA * NEMBED + col] = v;
        }
        if (tokB >= 0) {
            float4 v = acc1;
            v.x *= SCALE; v.y *= SCALE; v.z *= SCALE; v.w *= SCALE;
            *(float4*)&out[(size_t)tokB * NEMBED + col] = v;
        }
        int row2 = -1;
        if (h2 && tid < 16 && lreg >= 0) row2 = x[lreg] - start;
        __syncthreads();
        if (hn) { E4[tid * 2] = er0; E4[tid * 2 + 1] = er1; }
        if (h2 && tid < 16) { s_tok[sl * 32 + tid] = lreg; s_row[sl * 32 + tid] = row2; }
        __syncthreads();
    }
}

// ---------------- fused kernel ----------------
__global__ __launch_bounds__(NTHREADS, 4)
void fused_embed_kernel(const int* __restrict__ x,
                        const float* __restrict__ t0, const float* __restrict__ t1,
                        const float* __restrict__ t2, const float* __restrict__ t3,
                        const float* __restrict__ p1, const float* __restrict__ p2,
                        const float* __restrict__ p3,
                        const int* __restrict__ cnt,
                        const int* __restrict__ lists,
                        float* __restrict__ out) {
    // 72 KB shared region (2 blocks/CU):
    //  b1: E (16 KB) at smem
    //  b2: P (64 KB) at smem, E (8 KB) at smem+16384
    //  b3: P (16 KB) at smem, E (2 KB) at smem+4096
    __shared__ __align__(16) float smem[18432];
    __shared__ int s_tok[64], s_row[64];

    int bid = blockIdx.x;
    if (bid < G0) {
        run_copy(x, t0, lists, out, cnt[0], bid, G0, s_tok, s_row);
    } else if (bid < G0 + G1) {
        run_proj_g(x, t1, p1, lists + 1 * N_TOK, out, cnt[1], 20000,
                   bid - G0, G1, smem, s_tok, s_row);
    } else if (bid < G0 + G1 + G2) {
        int lb = bid - (G0 + G1);
        run_proj_lds<64>(x, t2, p2, lists + 2 * N_TOK, out, cnt[2], 40000,
                         lb & 3, lb >> 2, G2 / 4, smem, smem + 16384, s_tok, s_row);
    } else {
        int lb = bid - (G0 + G1 + G2);
        run_proj_lds<16>(x, t3, p3, lists + 3 * N_TOK, out, cnt[3], 200000,
                         lb & 3, lb >> 2, G3 / 4, smem, smem + 4096, s_tok, s_row);
    }
}

extern "C" void kernel_launch(void* const* d_in, const int* in_sizes, int n_in,
                              void* d_out, int out_size, void* d_ws, size_t ws_size,
                              hipStream_t stream) {
    const int*   x  = (const int*)d_in[0];
    const float* t0 = (const float*)d_in[1];
    const float* t1 = (const float*)d_in[2];
    const float* t2 = (const float*)d_in[3];
    const float* t3 = (const float*)d_in[4];
    const float* p1 = (const float*)d_in[5];
    const float* p2 = (const float*)d_in[6];
    const float* p3 = (const float*)d_in[7];
    float* out = (float*)d_out;

    int* cnt   = (int*)d_ws;
    int* lists = cnt + 64;

    hipMemsetAsync(d_ws, 0, 64 * sizeof(int), stream);
    classify_kernel<<<N_TOK / 256, 256, 0, stream>>>(x, cnt, lists);

    fused_embed_kernel<<<GRID, NTHREADS, 0, stream>>>(x, t0, t1, t2, t3, p1, p2, p3,
                                                      cnt, lists, out);
}